// Round 9
// baseline (166.043 us; speedup 1.0000x reference)
//
#include <hip/hip_runtime.h>
#include <hip/hip_bf16.h>

// y[b, c] = (sum_k x[b,k] * W[c % 512, k]) + bias[c]
// R14: staged-bytes reduction via tile geometry. R13's null (producer waves
// gave +-0) proved the global_load_lds rate is per-CU-pinned (~15.6 B/cy/CU
// at 2 blocks/CU) -> K-loop cost == staged bytes. With grid fixed at 512
// (2/CU), SPLITS = BM*BN/4096; moving 128x128/sp4 -> 128x256/sp8 cuts total
// staged bytes 256 -> 192 MB (-25%). Partial volume rises 32 -> 64 MB but
// fits L3; combine is XCD-ALIGNED (blockIdx&7 == mt&7 of its rows) so its
// reads hit the writers' home-XCD dirty L2/L3 lines, not HBM. sp8 partials
// exactly fill all 8 replica slots of out -- no workspace, no sync.
//   - BK=32, 3-stage ring (A 8 KB + B 16 KB per stage = 72 KB, the R7-proven
//     2-blocks/CU size), 6 DMA insts/wave/iter -> counted vmcnt(6), depth-2.
//   - fragment read: one 16x16x32 MFMA step per iter; chunk lq at LDS slot
//     lq^(row&3) (matches the (c&3)^(r&3) DMA swizzle). Wave grid 2x2 over
//     64x128 wave tiles, acc[4][8].
//   - convert kernel unchanged (x+W bf16; fusion closed: costs >=+30us).
// Falsifier (pre-committed): gemm >= 27us => BK=32 queue degraded the DMA
// rate; 128^2/BK=64 is the structural floor -> declare roofline next.

typedef __bf16 bf8 __attribute__((ext_vector_type(8)));
typedef float f4 __attribute__((ext_vector_type(4)));
typedef unsigned int uint;
typedef unsigned short ushort;

constexpr int M = 4096;
constexpr int K = 4096;
constexpr int NS = 512;
constexpr int OUTF = 4096;
constexpr int BM = 128, BN = 256, BK = 32;
constexpr int SPLITS = 8;
constexpr int KSPL = K / SPLITS;    // 512
constexpr int NITER = KSPL / BK;    // 16
constexpr int MT = M / BM;          // 32
constexpr int NT = NS / BN;         // 2

#define PERM_HI2(hi, lo) __builtin_amdgcn_perm((hi), (lo), 0x07060302u)
// s_waitcnt imm: vmcnt[3:0]|expcnt[6:4]|lgkmcnt[11:8]|vmcnt[15:14]
#define WAITCNT_VM6 0xF76   // vmcnt<=6: tile kk's 6 DMAs drained, kk+1 in flight
#define WAITCNT_VM0 0xF70

__device__ __forceinline__ void async16(const ushort* g, ushort* l) {
  __builtin_amdgcn_global_load_lds(
      (const __attribute__((address_space(1))) void*)g,
      (__attribute__((address_space(3))) void*)l, 16, 0, 0);
}

// fp32 -> bf16 (truncate), 8 elems/thread; covers x then W exactly (R0-proven).
__global__ __launch_bounds__(256)
void convert_kernel(const float* __restrict__ x, const float* __restrict__ w,
                    ushort* __restrict__ xb, ushort* __restrict__ wb) {
  const size_t i = (size_t)blockIdx.x * 256 + threadIdx.x;
  constexpr size_t NX = (size_t)M * K / 8;
  const float* src;
  ushort* dst;
  if (i < NX) { src = x + i * 8; dst = xb + i * 8; }
  else        { const size_t j = i - NX; src = w + j * 8; dst = wb + j * 8; }
  const uint4 a = *reinterpret_cast<const uint4*>(src);
  const uint4 b = *reinterpret_cast<const uint4*>(src + 4);
  uint4 o;
  o.x = PERM_HI2(a.y, a.x); o.y = PERM_HI2(a.w, a.z);
  o.z = PERM_HI2(b.y, b.x); o.w = PERM_HI2(b.w, b.z);
  *reinterpret_cast<uint4*>(dst) = o;
}

__global__ __launch_bounds__(256, 2)
void gemm_kernel(const ushort* __restrict__ xb, const ushort* __restrict__ wb,
                 float* __restrict__ out) {
  __shared__ __align__(16) ushort As[3][BM * BK];   //  8 KB/stage
  __shared__ __align__(16) ushort Bs[3][BN * BK];   // 16 KB/stage -> 72 KB total

  // block map: b&7 == mt&7 (XCD co-location of all 16 blocks of one mt).
  const int b   = blockIdx.x;          // 512 blocks
  const int low = b & 7, h = b >> 3;   // h in [0,64)
  const int mt  = (h >> 4) * 8 + low;  // 0..31
  const int sp  = (h >> 1) & 7;        // split 0..7
  const int nt  = h & 1;               // 0..1

  const int tid  = threadIdx.x;
  const int wv   = tid >> 6;           // 0..3
  const int lane = tid & 63;
  const int lr   = lane & 15;
  const int lq   = lane >> 4;

  // DMA maps: 16B chunk c of a tile covers row r=c>>2, global chunk
  // g=(c&3)^(r&3) (linear LDS dest, swizzled source). A: 512 chunks ->
  // 2 insts/wave; B: 1024 chunks -> 4 insts/wave.
  int goffA[2], llocA[2];
#pragma unroll
  for (int j = 0; j < 2; ++j) {
    const int c = (wv * 2 + j) * 64 + lane;
    const int r = c >> 2;
    const int g = (c & 3) ^ (r & 3);
    goffA[j] = r * K + g * 8;
    llocA[j] = c * 8;
  }
  int goffB[4], llocB[4];
#pragma unroll
  for (int j = 0; j < 4; ++j) {
    const int c = (wv * 4 + j) * 64 + lane;
    const int r = c >> 2;
    const int g = (c & 3) ^ (r & 3);
    goffB[j] = r * K + g * 8;
    llocB[j] = c * 8;
  }

  const ushort* xT = xb + (size_t)(mt * BM) * K + sp * KSPL;
  const ushort* wT = wb + (size_t)(nt * BN) * K + sp * KSPL;

  auto issue = [&](int tile, int stg) {
    const int ko = tile * BK;
#pragma unroll
    for (int j = 0; j < 2; ++j) async16(xT + ko + goffA[j], &As[stg][llocA[j]]);
#pragma unroll
    for (int j = 0; j < 4; ++j) async16(wT + ko + goffB[j], &Bs[stg][llocB[j]]);
  };

  // wave grid 2x2 over 64x128 wave tiles
  const int wm = (wv & 1) * 64;
  const int wn = (wv >> 1) * 128;
  const int coff = (lq ^ (lr & 3)) * 8;   // chunk lq at slot lq^(row&3); row&3==lr&3

  f4 acc[4][8] = {};

  // prologue: tiles 0,1 into stages 0,1 (6 DMAs/wave each)
  issue(0, 0);
  issue(1, 1);

  int st = 0;
  for (int kk = 0; kk < NITER; ++kk) {
    if (kk + 1 < NITER) __builtin_amdgcn_s_waitcnt(WAITCNT_VM6);
    else                __builtin_amdgcn_s_waitcnt(WAITCNT_VM0);
    __builtin_amdgcn_s_barrier();      // publish tile kk (stage st)
    asm volatile("" ::: "memory");

    // issue tile kk+2 into stage (kk+2)%3 == (kk-1)%3 (fully read; safe)
    if (kk + 2 < NITER) {
      int s2 = st + 2; if (s2 >= 3) s2 -= 3;
      issue(kk + 2, s2);
    }

    const ushort* aT = As[st];
    const ushort* bT = Bs[st];
    bf8 af[4], bfv[8];
#pragma unroll
    for (int mf = 0; mf < 4; ++mf)
      af[mf] = *reinterpret_cast<const bf8*>(&aT[(wm + mf * 16 + lr) * BK + coff]);
#pragma unroll
    for (int nf = 0; nf < 8; ++nf)
      bfv[nf] = *reinterpret_cast<const bf8*>(&bT[(wn + nf * 16 + lr) * BK + coff]);
#pragma unroll
    for (int mf = 0; mf < 4; ++mf)
#pragma unroll
      for (int nf = 0; nf < 8; ++nf)
        acc[mf][nf] = __builtin_amdgcn_mfma_f32_16x16x32_bf16(af[mf], bfv[nf], acc[mf][nf], 0, 0, 0);
    asm volatile("" ::: "memory");

    if (++st >= 3) st = 0;
  }

  // ---- epilogue: write fp32 partial into replica slot #sp of out ----
  // C/D layout (16x16x32, verified): row = wm+mf*16+lq*4+r, col = wn+nf*16+lr.
  float* pb = out + (size_t)(mt * BM) * OUTF + sp * NS + nt * BN;
#pragma unroll
  for (int mf = 0; mf < 4; ++mf)
#pragma unroll
    for (int nf = 0; nf < 8; ++nf)
#pragma unroll
      for (int r = 0; r < 4; ++r)
        pb[(size_t)(wm + mf * 16 + lq * 4 + r) * OUTF + wn + nf * 16 + lr] =
            acc[mf][nf][r];
}

// y[r][rep][c] = sum_{sp<8} out[r][sp][c] + bias[rep][c], rep = 0..7.
// XCD-aligned: blockIdx&7 picks the XCD; this block only touches rows whose
// mt&7 matches -> partial reads hit the writers' home-L2/L3 dirty lines.
// In-place safe: each thread reads exactly the 8 addresses it then writes.
__global__ __launch_bounds__(256)
void combine_kernel(const float* __restrict__ bias, float* __restrict__ out) {
  const int xcd = blockIdx.x & 7;
  const int q   = blockIdx.x >> 3;              // 0..255
  const int idx = q * 256 + threadIdx.x;        // 0..65535
  const int lrow = idx >> 7;                    // 0..511
  const int c4   = idx & 127;                   // float4-col within 512
  const int mt   = xcd + (lrow >> 7) * 8;       // 4 mt groups per XCD
  const int row  = mt * 128 + (lrow & 127);
  float* orow = out + (size_t)row * OUTF;
  float4 s;
  {
    const float4 p0 = *reinterpret_cast<const float4*>(orow + 0 * NS + c4 * 4);
    const float4 p1 = *reinterpret_cast<const float4*>(orow + 1 * NS + c4 * 4);
    const float4 p2 = *reinterpret_cast<const float4*>(orow + 2 * NS + c4 * 4);
    const float4 p3 = *reinterpret_cast<const float4*>(orow + 3 * NS + c4 * 4);
    const float4 p4 = *reinterpret_cast<const float4*>(orow + 4 * NS + c4 * 4);
    const float4 p5 = *reinterpret_cast<const float4*>(orow + 5 * NS + c4 * 4);
    const float4 p6 = *reinterpret_cast<const float4*>(orow + 6 * NS + c4 * 4);
    const float4 p7 = *reinterpret_cast<const float4*>(orow + 7 * NS + c4 * 4);
    s.x = ((p0.x + p1.x) + (p2.x + p3.x)) + ((p4.x + p5.x) + (p6.x + p7.x));
    s.y = ((p0.y + p1.y) + (p2.y + p3.y)) + ((p4.y + p5.y) + (p6.y + p7.y));
    s.z = ((p0.z + p1.z) + (p2.z + p3.z)) + ((p4.z + p5.z) + (p6.z + p7.z));
    s.w = ((p0.w + p1.w) + (p2.w + p3.w)) + ((p4.w + p5.w) + (p6.w + p7.w));
  }
  const float4* bias4 = reinterpret_cast<const float4*>(bias);
#pragma unroll
  for (int rep = 0; rep < 8; ++rep) {
    const float4 bb = bias4[rep * 128 + c4];
    float4 o;
    o.x = s.x + bb.x; o.y = s.y + bb.y;
    o.z = s.z + bb.z; o.w = s.w + bb.w;
    *reinterpret_cast<float4*>(orow + rep * NS + c4 * 4) = o;
  }
}

extern "C" void kernel_launch(void* const* d_in, const int* in_sizes, int n_in,
                              void* d_out, int out_size, void* d_ws, size_t ws_size,
                              hipStream_t stream) {
  (void)in_sizes; (void)n_in; (void)out_size; (void)ws_size;
  const float* x    = (const float*)d_in[0];
  const float* w    = (const float*)d_in[1];
  const float* bias = (const float*)d_in[2];
  float* out = (float*)d_out;

  ushort* xb = (ushort*)d_ws;                       // 32 MB bf16 x
  ushort* wb = (ushort*)d_ws + (size_t)M * K;       // 4 MB bf16 W (ws >= 36 MB)

  constexpr int conv_blocks = (int)(((size_t)M * K / 8 + (size_t)NS * K / 8) / 256); // 9216
  convert_kernel<<<dim3(conv_blocks), dim3(256), 0, stream>>>(x, w, xb, wb);
  gemm_kernel<<<dim3(MT * NT * SPLITS), dim3(256), 0, stream>>>(xb, wb, out);
  combine_kernel<<<dim3(M * (NS / 4) / 256), dim3(256), 0, stream>>>(bias, out);
}